// Round 8
// baseline (72.644 us; speedup 1.0000x reference)
//
#include <hip/hip_runtime.h>
#include <math.h>

// DRR via Siddon ray tracing, 256^3 volume, 256x256 detector.
// Block = 1024 threads = 64 consecutive rays (lane-fast) x 16 alpha-partitions
// (slow). A wave is 64 adjacent rays at the SAME partition -> per-instant
// volume loads land in ~4-8 cache lines (same x-slab, consecutive z) instead
// of 16, and lane divergence is minimal. Partials combined via LDS tree.
// Cells derived per-segment via midpoint-trunc (bit-faithful to reference
// rounding). Out-of-range plane alphas exceed amax by >= one alpha-quantum,
// so plane-advance needs no range checks.

#define NPLANE 256
constexpr int TPR   = 16;
constexpr int BLOCK = 1024;          // 64 rays x 16 partitions

__device__ __forceinline__ float palpha(int i, float sp, float src, float rd) {
    return fmaf((float)i, sp, -src) * rd;
}
__device__ __forceinline__ float palpha_f(float fi, float sp, float nsrc, float rd) {
    return fmaf(fi, sp, nsrc) * rd;
}

__global__ __launch_bounds__(BLOCK) void drr_kernel(
    const float* __restrict__ vol,
    const float* __restrict__ spacing,
    const float* __restrict__ sdrp,
    const float* __restrict__ rot,
    const float* __restrict__ trans,
    float* __restrict__ out)
{
    int tid   = threadIdx.x;
    int lb    = ((int)blockIdx.x * 397) & 1023;   // bijective tail-balance swizzle
    int part  = (tid >> 6) & (TPR - 1);
    int rlane = tid & 63;
    int rl    = rlane | (lb << 6);                // 0..65535 linear ray id

    // R = Rz(theta) @ Ry(phi) @ Rx(gamma): columns 0 (ray dir), 1 (u), 2 (v)
    float theta = rot[0], phi = rot[1], gam = rot[2];
    float ct = cosf(theta), st = sinf(theta);
    float cp = cosf(phi),   sp_ = sinf(phi);
    float cg = cosf(gam),   sg = sinf(gam);

    float r0x = ct * cp, r0y = st * cp, r0z = -sp_;
    float ux = ct * sp_ * sg - st * cg, uy = st * sp_ * sg + ct * cg, uz = cp * sg;
    float vx = ct * sp_ * cg + st * sg, vy = st * sp_ * cg - ct * sg, vz = cp * cg;

    // lane-fast detector axis = least stride-weighted volume motion (uniform)
    float cost_u = fabsf(ux) * 65536.f + fabsf(uy) * 256.f + fabsf(uz);
    float cost_v = fabsf(vx) * 65536.f + fabsf(vy) * 256.f + fabsf(vz);
    bool tfast = cost_u < cost_v;
    int ti = tfast ? (rl & 255) : (rl >> 8);
    int si = tfast ? (rl >> 8) : (rl & 255);

    float sdr = sdrp[0];
    float tx = trans[0], ty = trans[1], tz = trans[2];

    float sx = sdr * r0x + tx,  sy = sdr * r0y + ty,  sz = sdr * r0z + tz;
    float cxx = -sdr * r0x + tx, cxy = -sdr * r0y + ty, cxz = -sdr * r0z + tz;

    float tval = (float)(ti - 127) * 2.0f;
    float sval = (float)(si - 127) * 2.0f;

    float gx = tval * ux + sval * vx + cxx;
    float gy = tval * uy + sval * vy + cxy;
    float gz = tval * uz + sval * vz + cxz;

    float sdx = gx - sx + 1e-8f;
    float sdy = gy - sy + 1e-8f;
    float sdz = gz - sz + 1e-8f;

    float spx = spacing[0], spy = spacing[1], spz = spacing[2];
    float rdx = 1.0f / sdx, rdy = 1.0f / sdy, rdz = 1.0f / sdz;

    float a0x = palpha(0, spx, sx, rdx), a1x = palpha(NPLANE, spx, sx, rdx);
    float a0y = palpha(0, spy, sy, rdy), a1y = palpha(NPLANE, spy, sy, rdy);
    float a0z = palpha(0, spz, sz, rdz), a1z = palpha(NPLANE, spz, sz, rdz);

    float amin = fmaxf(fmaxf(fminf(a0x, a1x), fminf(a0y, a1y)), fminf(a0z, a1z));
    float amax = fminf(fminf(fmaxf(a0x, a1x), fmaxf(a0y, a1y)), fmaxf(a0z, a1z));

    float acc = 0.f;

    if (amax > amin) {
        float range = amax - amin;
        constexpr float inv = 1.0f / (float)TPR;
        float lo = fmaf(range, (float)part * inv, amin);
        float hi = (part == TPR - 1) ? INFINITY
                                     : fmaf(range, (float)(part + 1) * inv, amin);
        float end = fminf(hi, amax);

        int iix, iiy, iiz, dix, diy, diz;
        float nxx, nxy, nxz;

        // first plane crossing with alpha >= lo per axis
        #define SETUP(SP, SRC, SDD, RD, I, DI, NXT)                                \
        {                                                                          \
            float q = fmaf(lo, SDD, SRC) / (SP);                                   \
            q = fminf(fmaxf(q, -1.f), 257.f);                                      \
            if ((SDD) > 0.f) {                                                     \
                DI = 1;                                                            \
                I = (int)ceilf(q);                                                 \
                while (I > 0 && palpha(I - 1, SP, SRC, RD) >= lo) --I;             \
                while (I <= NPLANE && palpha(I, SP, SRC, RD) < lo) ++I;            \
                NXT = (I <= NPLANE) ? palpha(I, SP, SRC, RD) : INFINITY;           \
            } else {                                                               \
                DI = -1;                                                           \
                I = (int)floorf(q);                                                \
                while (I < NPLANE && palpha(I + 1, SP, SRC, RD) >= lo) ++I;        \
                while (I >= 0 && palpha(I, SP, SRC, RD) < lo) --I;                 \
                NXT = (I >= 0) ? palpha(I, SP, SRC, RD) : INFINITY;                \
            }                                                                      \
        }

        SETUP(spx, sx, sdx, rdx, iix, dix, nxx)
        SETUP(spy, sy, sdy, rdy, iiy, diy, nxy)
        SETUP(spz, sz, sdz, rdz, iiz, diz, nxz)
        #undef SETUP

        float fix = (float)iix, fiy = (float)iiy, fiz = (float)iiz;
        float dfx = (float)dix, dfy = (float)diy, dfz = (float)diz;
        float nsx = -sx, nsy = -sy, nsz = -sz;

        // 1/spacing: at spacing==1 this is exactly 1.0 and *1.0 is an IEEE
        // identity, so positions match the reference's division bit-for-bit.
        float ispx = 1.0f / spx, ispy = 1.0f / spy, ispz = 1.0f / spz;

        #define ADV()                                                              \
            if (nxx == cur) { fix += dfx; nxx = palpha_f(fix, spx, nsx, rdx); }    \
            if (nxy == cur) { fiy += dfy; nxy = palpha_f(fiy, spy, nsy, rdy); }    \
            if (nxz == cur) { fiz += dfz; nxz = palpha_f(fiz, spz, nsz, rdz); }

        #define SEG(CUR, E, ADDR)                                                  \
        {                                                                          \
            float amid = 0.5f * ((CUR) + (E));                                     \
            float pxv = fmaf(amid, sdx, sx) * ispx;                                \
            float pyv = fmaf(amid, sdy, sy) * ispy;                                \
            float pzv = fmaf(amid, sdz, sz) * ispz;                                \
            int jx = (int)pxv; jx = jx < 0 ? 0 : (jx > 255 ? 255 : jx);            \
            int jy = (int)pyv; jy = jy < 0 ? 0 : (jy > 255 ? 255 : jy);            \
            int jz = (int)pzv; jz = jz < 0 ? 0 : (jz > 255 ? 255 : jz);            \
            ADDR = (jx << 16) + (jy << 8) + jz;                                    \
        }

        float cur = fminf(fminf(nxx, nxy), nxz);

        if (cur < end) {
            ADV();
            float nxt = fminf(fminf(nxx, nxy), nxz);
            float e   = fminf(nxt, amax);
            int a; SEG(cur, e, a)
            float sA = e - cur;
            float vA = vol[a];
            cur = nxt;

            while (cur < end) {
                ADV();
                nxt = fminf(fminf(nxx, nxy), nxz);
                e   = fminf(nxt, amax);
                SEG(cur, e, a)
                float vB = vol[a];                 // issue B
                acc = fmaf(vA, sA, acc);           // consume A
                float sB = e - cur;
                cur = nxt;
                if (cur >= end) { acc = fmaf(vB, sB, acc); goto traced; }

                ADV();
                nxt = fminf(fminf(nxx, nxy), nxz);
                e   = fminf(nxt, amax);
                SEG(cur, e, a)
                vA = vol[a];                       // issue A'
                acc = fmaf(vB, sB, acc);           // consume B
                sA = e - cur;
                cur = nxt;
            }
            acc = fmaf(vA, sA, acc);               // drain
            traced: ;
        }
        #undef ADV
        #undef SEG
    }

    // block-level reduction: 16 partitions per ray, partition is the
    // slow thread index (stride 64)
    __shared__ float red[BLOCK];
    red[tid] = acc;
    __syncthreads();
    #pragma unroll
    for (int off = TPR / 2; off > 0; off >>= 1) {
        if (part < off) red[tid] = red[tid] + red[tid + off * 64];
        __syncthreads();
    }

    if (part == 0) {
        float rl2 = sqrtf(sdx * sdx + sdy * sdy + sdz * sdz);
        out[ti * 256 + si] = red[tid] * rl2;
    }
}

extern "C" void kernel_launch(void* const* d_in, const int* in_sizes, int n_in,
                              void* d_out, int out_size, void* d_ws, size_t ws_size,
                              hipStream_t stream) {
    const float* vol     = (const float*)d_in[0];
    const float* spacing = (const float*)d_in[1];
    const float* sdr     = (const float*)d_in[2];
    const float* rot     = (const float*)d_in[3];
    const float* trans   = (const float*)d_in[4];
    float* out = (float*)d_out;

    int nblocks = 256 * 256 * TPR / BLOCK;   // 1024
    drr_kernel<<<nblocks, BLOCK, 0, stream>>>(vol, spacing, sdr, rot, trans, out);
}